// Round 1
// baseline (8530.705 us; speedup 1.0000x reference)
//
#include <hip/hip_runtime.h>

// Problem: out = sum_i ChebConv_i(x),  K=3, normalization=None, lambda_max=2.
// lhat(v) = scatter_dst(-w * v[src]) + (deg-1) ⊙ v
// Tx0 = x; Tx1 = lhat(x); Tx2 = 2*lhat(Tx1) - x
// out = x @ (Σ_i W[i,0]) + Σ_i (Tx1_i @ W[i,1] + Tx2_i @ W[i,2]) + Σ_i b_i

#define CDIM 128
static const float SCALE = 1.0f;  // 2 / LAMBDA_MAX

// ---------------- deg: deg[src] += w ----------------
__global__ __launch_bounds__(256) void deg_kernel(const int* __restrict__ srcv,
    const float* __restrict__ ew, float* __restrict__ deg, int E) {
  int e = blockIdx.x * 256 + threadIdx.x;
  if (e >= E) return;
  unsafeAtomicAdd(&deg[srcv[e]], ew[e]);
}

// diag = scale*deg - 1
__global__ __launch_bounds__(256) void diag_finish(float* __restrict__ diag, int total) {
  int p = blockIdx.x * 256 + threadIdx.x;
  if (p >= total) return;
  diag[p] = SCALE * diag[p] - 1.0f;
}

// w0s = sum_i W[i,0]; bs = sum_i b[i]
__global__ __launch_bounds__(256) void wsum_kernel(const float* __restrict__ W,
    const float* __restrict__ b, float* __restrict__ w0s, float* __restrict__ bs,
    int KK, int NCv) {
  int p = blockIdx.x * 256 + threadIdx.x;
  if (p < CDIM * CDIM) {
    float s = 0.f;
    for (int i = 0; i < NCv; ++i) s += W[(size_t)i * KK * CDIM * CDIM + p];
    w0s[p] = s;
  }
  if (p < CDIM) {
    float s = 0.f;
    for (int i = 0; i < NCv; ++i) s += b[i * CDIM + p];
    bs[p] = s;
  }
}

// buf = diag[n] * x   (float4 over channels)
__global__ __launch_bounds__(256) void init_tx1(const float* __restrict__ x,
    const float* __restrict__ diag, float* __restrict__ buf, int total4) {
  int gid = blockIdx.x * 256 + threadIdx.x;
  if (gid >= total4) return;
  int n = gid >> 5;  // 32 float4 per row
  float d = diag[n];
  float4 v = reinterpret_cast<const float4*>(x)[gid];
  v.x *= d; v.y *= d; v.z *= d; v.w *= d;
  reinterpret_cast<float4*>(buf)[gid] = v;
}

// buf2 = 2*diag[n]*buf1 - x
__global__ __launch_bounds__(256) void init_tx2(const float* __restrict__ x,
    const float* __restrict__ buf1, const float* __restrict__ diag,
    float* __restrict__ buf2, int total4) {
  int gid = blockIdx.x * 256 + threadIdx.x;
  if (gid >= total4) return;
  int n = gid >> 5;
  float d = 2.0f * diag[n];
  float4 v = reinterpret_cast<const float4*>(buf1)[gid];
  float4 xv = reinterpret_cast<const float4*>(x)[gid];
  v.x = d * v.x - xv.x; v.y = d * v.y - xv.y;
  v.z = d * v.z - xv.z; v.w = d * v.w - xv.w;
  reinterpret_cast<float4*>(buf2)[gid] = v;
}

// out[dst] += coef * w * V[src]   (32 lanes per edge, float4 per lane)
__global__ __launch_bounds__(256) void scatter_kernel(const int* __restrict__ srcv,
    const int* __restrict__ dstv, const float* __restrict__ ew,
    const float* __restrict__ V, float* __restrict__ outb, float coef, int E) {
  int gid = blockIdx.x * 256 + threadIdx.x;
  int e = gid >> 5;
  if (e >= E) return;
  int c4 = (gid & 31) << 2;
  int s = srcv[e], d = dstv[e];
  float wv = coef * ew[e];
  const float4 v = *reinterpret_cast<const float4*>(V + ((size_t)s << 7) + c4);
  float* o = outb + ((size_t)d << 7) + c4;
  unsafeAtomicAdd(o + 0, v.x * wv);
  unsafeAtomicAdd(o + 1, v.y * wv);
  unsafeAtomicAdd(o + 2, v.z * wv);
  unsafeAtomicAdd(o + 3, v.w * wv);
}

// C[32 rows x 128 cols] (+)= A_tile @ B ; optional bias (writes) else accumulate
__global__ __launch_bounds__(256) void gemm_acc(const float* __restrict__ A,
    const float* __restrict__ B, float* __restrict__ Cmat,
    const float* __restrict__ bias01, int N) {
  __shared__ float Alds[32 * CDIM];
  int t = threadIdx.x;
  int row0 = blockIdx.x * 32;
  #pragma unroll
  for (int j = 0; j < 16; ++j) {
    int idx = t + j * 256;
    int r = row0 + (idx >> 7);
    Alds[idx] = (r < N) ? A[(size_t)r * CDIM + (idx & 127)] : 0.f;
  }
  __syncthreads();
  int c = t & 127;
  int rb = (t >> 7) * 16;
  float acc[16];
  #pragma unroll
  for (int j = 0; j < 16; ++j) acc[j] = 0.f;
  for (int k = 0; k < CDIM; k += 4) {
    float b0 = B[(k + 0) * CDIM + c];
    float b1 = B[(k + 1) * CDIM + c];
    float b2 = B[(k + 2) * CDIM + c];
    float b3 = B[(k + 3) * CDIM + c];
    #pragma unroll
    for (int j = 0; j < 16; ++j) {
      const float4 a = *reinterpret_cast<const float4*>(&Alds[(rb + j) * CDIM + k]);
      acc[j] = fmaf(a.x, b0, fmaf(a.y, b1, fmaf(a.z, b2, fmaf(a.w, b3, acc[j]))));
    }
  }
  if (bias01) {
    float bb = bias01[c];
    #pragma unroll
    for (int j = 0; j < 16; ++j) {
      int r = row0 + rb + j;
      if (r < N) Cmat[(size_t)r * CDIM + c] = acc[j] + bb;
    }
  } else {
    #pragma unroll
    for (int j = 0; j < 16; ++j) {
      int r = row0 + rb + j;
      if (r < N) Cmat[(size_t)r * CDIM + c] += acc[j];
    }
  }
}

extern "C" void kernel_launch(void* const* d_in, const int* in_sizes, int n_in,
                              void* d_out, int out_size, void* d_ws, size_t ws_size,
                              hipStream_t stream) {
  const float* x  = (const float*)d_in[0];
  const int*   ei = (const int*)d_in[1];    // [NC, 2, E] int32
  const float* ew = (const float*)d_in[2];  // [NC, E]
  const float* W  = (const float*)d_in[3];  // [NC, K, 128, 128]
  const float* b  = (const float*)d_in[4];  // [NC, 128]

  const int Nn  = in_sizes[0] / CDIM;
  const int NCv = in_sizes[4] / CDIM;
  const int E   = in_sizes[2] / NCv;
  const int KK  = in_sizes[3] / (NCv * CDIM * CDIM);

  float* diag = (float*)d_ws;              // NC * N
  float* w0s  = diag + (size_t)NCv * Nn;   // 128*128
  float* bs   = w0s + CDIM * CDIM;         // 128
  float* buf1 = bs + CDIM;                 // N * 128
  float* buf2 = buf1 + (size_t)Nn * CDIM;  // N * 128

  hipMemsetAsync(diag, 0, (size_t)NCv * Nn * sizeof(float), stream);

  // degrees for all convs
  for (int i = 0; i < NCv; ++i) {
    deg_kernel<<<(E + 255) / 256, 256, 0, stream>>>(
        ei + (size_t)i * 2 * E, ew + (size_t)i * E, diag + (size_t)i * Nn, E);
  }
  diag_finish<<<(NCv * Nn + 255) / 256, 256, 0, stream>>>(diag, NCv * Nn);
  wsum_kernel<<<(CDIM * CDIM + 255) / 256, 256, 0, stream>>>(W, b, w0s, bs, KK, NCv);

  const int gemm_grid = (Nn + 31) / 32;
  const int total4 = Nn * (CDIM / 4);
  const int init_grid = (total4 + 255) / 256;
  const int scat_grid = (E * 32 + 255) / 256;

  // out = x @ W0sum + bias_sum
  gemm_acc<<<gemm_grid, 256, 0, stream>>>(x, w0s, (float*)d_out, bs, Nn);

  for (int i = 0; i < NCv; ++i) {
    const int* srcv = ei + (size_t)i * 2 * E;
    const int* dstv = srcv + E;
    const float* wv = ew + (size_t)i * E;
    const float* di = diag + (size_t)i * Nn;
    const float* Wi = W + (size_t)i * KK * CDIM * CDIM;

    // Tx1 = lhat(x)
    init_tx1<<<init_grid, 256, 0, stream>>>(x, di, buf1, total4);
    scatter_kernel<<<scat_grid, 256, 0, stream>>>(srcv, dstv, wv, x, buf1, -SCALE, E);
    gemm_acc<<<gemm_grid, 256, 0, stream>>>(buf1, Wi + (size_t)1 * CDIM * CDIM,
                                            (float*)d_out, nullptr, Nn);
    // Tx2 = 2*lhat(Tx1) - x
    init_tx2<<<init_grid, 256, 0, stream>>>(x, buf1, di, buf2, total4);
    scatter_kernel<<<scat_grid, 256, 0, stream>>>(srcv, dstv, wv, buf1, buf2,
                                                  -2.0f * SCALE, E);
    gemm_acc<<<gemm_grid, 256, 0, stream>>>(buf2, Wi + (size_t)2 * CDIM * CDIM,
                                            (float*)d_out, nullptr, Nn);
  }
}

// Round 2
// 1933.447 us; speedup vs baseline: 4.4122x; 4.4122x over previous
//
#include <hip/hip_runtime.h>

// out = Σ_i ChebConv_i(x),  K=3, normalization=None, lambda_max=2 (SCALE=1).
// lhat(v) = (deg-1)⊙v - Σ_{e: dst=n} w_e v[src_e]
// Tx1 = lhat(x); Tx2 = 2*lhat(Tx1) - x
// out = x @ ΣW[i,0] + Σ_i (Tx1_i @ W[i,1] + Tx2_i @ W[i,2]) + Σ_i b_i
//
// Round 2: replace float-atomic scatter (1.6GB RMW write traffic/pass) with
// dst-CSR gather SpMV (register accumulate, one store per row/channel).

#define CDIM 128

// ---------------- deg: deg[src] += w ----------------
__global__ __launch_bounds__(256) void deg_kernel(const int* __restrict__ srcv,
    const float* __restrict__ ew, float* __restrict__ deg, int E) {
  int e = blockIdx.x * 256 + threadIdx.x;
  if (e >= E) return;
  unsafeAtomicAdd(&deg[srcv[e]], ew[e]);
}

// diag = deg - 1   (SCALE = 1)
__global__ __launch_bounds__(256) void diag_finish(float* __restrict__ diag, int total) {
  int p = blockIdx.x * 256 + threadIdx.x;
  if (p >= total) return;
  diag[p] = diag[p] - 1.0f;
}

// w0s = sum_i W[i,0]; bs = sum_i b[i]
__global__ __launch_bounds__(256) void wsum_kernel(const float* __restrict__ W,
    const float* __restrict__ b, float* __restrict__ w0s, float* __restrict__ bs,
    int KK, int NCv) {
  int p = blockIdx.x * 256 + threadIdx.x;
  if (p < CDIM * CDIM) {
    float s = 0.f;
    for (int i = 0; i < NCv; ++i) s += W[(size_t)i * KK * CDIM * CDIM + p];
    w0s[p] = s;
  }
  if (p < CDIM) {
    float s = 0.f;
    for (int i = 0; i < NCv; ++i) s += b[i * CDIM + p];
    bs[p] = s;
  }
}

// ---------------- CSR build ----------------
__global__ __launch_bounds__(256) void hist_kernel(const int* __restrict__ dstv,
    int* __restrict__ cnt, int E) {
  int e = blockIdx.x * 256 + threadIdx.x;
  if (e >= E) return;
  atomicAdd(&cnt[dstv[e]], 1);
}

// single-block exclusive scan: row_ptr[0..N] from cnt[0..N-1]; pos <- row_ptr[i]
// (cnt and pos may alias: each element read once then written once by same thread)
__global__ __launch_bounds__(1024) void scan_kernel(const int* __restrict__ cnt,
    int* __restrict__ row_ptr, int* __restrict__ pos, int N) {
  __shared__ int lds[1024];
  __shared__ int carry_s;
  if (threadIdx.x == 0) carry_s = 0;
  __syncthreads();
  for (int base = 0; base < N; base += 1024) {
    int i = base + (int)threadIdx.x;
    int v = (i < N) ? cnt[i] : 0;
    lds[threadIdx.x] = v;
    __syncthreads();
    for (int off = 1; off < 1024; off <<= 1) {
      int t = (threadIdx.x >= off) ? lds[threadIdx.x - off] : 0;
      __syncthreads();
      lds[threadIdx.x] += t;
      __syncthreads();
    }
    int excl = carry_s + lds[threadIdx.x] - v;
    if (i < N) { row_ptr[i] = excl; pos[i] = excl; }
    __syncthreads();
    if (threadIdx.x == 0) carry_s += lds[1023];
    __syncthreads();
  }
  if (threadIdx.x == 0) row_ptr[N] = carry_s;
}

__global__ __launch_bounds__(256) void fill_csr(const int* __restrict__ srcv,
    const int* __restrict__ dstv, const float* __restrict__ ew,
    int* __restrict__ pos, int2* __restrict__ srcw, int E) {
  int e = blockIdx.x * 256 + threadIdx.x;
  if (e >= E) return;
  int p = atomicAdd(&pos[dstv[e]], 1);
  srcw[p] = make_int2(srcv[e], __float_as_int(ew[e]));
}

// ---------------- fused lhat (gather SpMV) ----------------
// out[row][c] = alpha * (diag[row]*V[row][c] - Σ_e w_e V[src_e][c]) + beta*X[row][c]
__global__ __launch_bounds__(256) void spmv_kernel(const int* __restrict__ row_ptr,
    const int2* __restrict__ srcw, const float* __restrict__ diag,
    const float* __restrict__ V, const float* __restrict__ X,
    float* __restrict__ out, float alpha, float beta, int N) {
  int row = blockIdx.x * 2 + (threadIdx.x >> 7);
  if (row >= N) return;
  int c = threadIdx.x & 127;
  int beg = row_ptr[row], end = row_ptr[row + 1];
  float acc = diag[row] * V[((size_t)row << 7) + c];
  for (int e = beg; e < end; ++e) {
    int2 sw = srcw[e];  // wave-broadcast load
    acc = fmaf(-__int_as_float(sw.y), V[((size_t)sw.x << 7) + c], acc);
  }
  float r = alpha * acc;
  if (beta != 0.f) r = fmaf(beta, X[((size_t)row << 7) + c], r);
  out[((size_t)row << 7) + c] = r;
}

// C[32 rows x 128 cols] (+)= A_tile @ B ; optional bias (writes) else accumulate
__global__ __launch_bounds__(256) void gemm_acc(const float* __restrict__ A,
    const float* __restrict__ B, float* __restrict__ Cmat,
    const float* __restrict__ bias01, int N) {
  __shared__ float Alds[32 * CDIM];
  int t = threadIdx.x;
  int row0 = blockIdx.x * 32;
  #pragma unroll
  for (int j = 0; j < 16; ++j) {
    int idx = t + j * 256;
    int r = row0 + (idx >> 7);
    Alds[idx] = (r < N) ? A[(size_t)r * CDIM + (idx & 127)] : 0.f;
  }
  __syncthreads();
  int c = t & 127;
  int rb = (t >> 7) * 16;
  float acc[16];
  #pragma unroll
  for (int j = 0; j < 16; ++j) acc[j] = 0.f;
  for (int k = 0; k < CDIM; k += 4) {
    float b0 = B[(k + 0) * CDIM + c];
    float b1 = B[(k + 1) * CDIM + c];
    float b2 = B[(k + 2) * CDIM + c];
    float b3 = B[(k + 3) * CDIM + c];
    #pragma unroll
    for (int j = 0; j < 16; ++j) {
      const float4 a = *reinterpret_cast<const float4*>(&Alds[(rb + j) * CDIM + k]);
      acc[j] = fmaf(a.x, b0, fmaf(a.y, b1, fmaf(a.z, b2, fmaf(a.w, b3, acc[j]))));
    }
  }
  if (bias01) {
    float bb = bias01[c];
    #pragma unroll
    for (int j = 0; j < 16; ++j) {
      int r = row0 + rb + j;
      if (r < N) Cmat[(size_t)r * CDIM + c] = acc[j] + bb;
    }
  } else {
    #pragma unroll
    for (int j = 0; j < 16; ++j) {
      int r = row0 + rb + j;
      if (r < N) Cmat[(size_t)r * CDIM + c] += acc[j];
    }
  }
}

extern "C" void kernel_launch(void* const* d_in, const int* in_sizes, int n_in,
                              void* d_out, int out_size, void* d_ws, size_t ws_size,
                              hipStream_t stream) {
  const float* x  = (const float*)d_in[0];
  const int*   ei = (const int*)d_in[1];    // [NC, 2, E] int32
  const float* ew = (const float*)d_in[2];  // [NC, E]
  const float* W  = (const float*)d_in[3];  // [NC, K, 128, 128]
  const float* b  = (const float*)d_in[4];  // [NC, 128]

  const int Nn  = in_sizes[0] / CDIM;
  const int NCv = in_sizes[4] / CDIM;
  const int E   = in_sizes[2] / NCv;
  const int KK  = in_sizes[3] / (NCv * CDIM * CDIM);

  float* diag  = (float*)d_ws;               // NC * N
  float* w0s   = diag + (size_t)NCv * Nn;    // 128*128
  float* bs    = w0s + CDIM * CDIM;          // 128
  float* buf1  = bs + CDIM;                  // N * 128
  float* buf2  = buf1 + (size_t)Nn * CDIM;   // N * 128
  int*   row_ptr = (int*)(buf2 + (size_t)Nn * CDIM);  // N+1
  int*   posb  = row_ptr + (Nn + 1);         // N (cnt, then fill cursor)
  int2*  srcw  = (int2*)(posb + Nn + 1);     // E pairs

  hipMemsetAsync(diag, 0, (size_t)NCv * Nn * sizeof(float), stream);

  for (int i = 0; i < NCv; ++i) {
    deg_kernel<<<(E + 255) / 256, 256, 0, stream>>>(
        ei + (size_t)i * 2 * E, ew + (size_t)i * E, diag + (size_t)i * Nn, E);
  }
  diag_finish<<<(NCv * Nn + 255) / 256, 256, 0, stream>>>(diag, NCv * Nn);
  wsum_kernel<<<(CDIM * CDIM + 255) / 256, 256, 0, stream>>>(W, b, w0s, bs, KK, NCv);

  const int gemm_grid = (Nn + 31) / 32;
  const int eg = (E + 255) / 256;
  const int spmv_grid = (Nn + 1) / 2;

  // out = x @ W0sum + bias_sum
  gemm_acc<<<gemm_grid, 256, 0, stream>>>(x, w0s, (float*)d_out, bs, Nn);

  for (int i = 0; i < NCv; ++i) {
    const int* srcv = ei + (size_t)i * 2 * E;
    const int* dstv = srcv + E;
    const float* wv = ew + (size_t)i * E;
    const float* di = diag + (size_t)i * Nn;
    const float* Wi = W + (size_t)i * KK * CDIM * CDIM;

    // build dst-CSR for this conv
    hipMemsetAsync(posb, 0, (size_t)Nn * sizeof(int), stream);
    hist_kernel<<<eg, 256, 0, stream>>>(dstv, posb, E);
    scan_kernel<<<1, 1024, 0, stream>>>(posb, row_ptr, posb, Nn);
    fill_csr<<<eg, 256, 0, stream>>>(srcv, dstv, wv, posb, srcw, E);

    // Tx1 = lhat(x)
    spmv_kernel<<<spmv_grid, 256, 0, stream>>>(row_ptr, srcw, di, x, nullptr,
                                               buf1, 1.0f, 0.0f, Nn);
    gemm_acc<<<gemm_grid, 256, 0, stream>>>(buf1, Wi + (size_t)1 * CDIM * CDIM,
                                            (float*)d_out, nullptr, Nn);
    // Tx2 = 2*lhat(Tx1) - x
    spmv_kernel<<<spmv_grid, 256, 0, stream>>>(row_ptr, srcw, di, buf1, x,
                                               buf2, 2.0f, -1.0f, Nn);
    gemm_acc<<<gemm_grid, 256, 0, stream>>>(buf2, Wi + (size_t)2 * CDIM * CDIM,
                                            (float*)d_out, nullptr, Nn);
  }
}

// Round 3
// 1092.755 us; speedup vs baseline: 7.8066x; 1.7693x over previous
//
#include <hip/hip_runtime.h>

// out = Σ_i ChebConv_i(x), K=3, normalization=None, lambda_max=2 (scale=1).
// lhat(v)[r] = (deg[r]-1)*v[r] - Σ_{e:dst=r} w_e v[src_e]
// Tx1 = lhat(x); Tx2 = 2*lhat(Tx1) - x
// out = x@ΣW[i,0] + Σ_i (Tx1_i@W[i,1] + Tx2_i@W[i,2]) + Σ_i b_i
//
// Round 3: bf16 intermediates (halve gather bytes), per-conv fused GEMM
// (2 A-tiles, one C RMW), batched CSR build with wave-shuffle scan.

#define CDIM 128

__device__ __forceinline__ float b2f(unsigned short h) {
  return __uint_as_float((unsigned)h << 16);
}
__device__ __forceinline__ unsigned short f2b(float f) {
  unsigned u = __float_as_uint(f);
  return (unsigned short)((u + 0x7FFF + ((u >> 16) & 1)) >> 16);
}

// x (f32) -> xb (bf16 pairs)
__global__ __launch_bounds__(256) void xcast_kernel(const float2* __restrict__ x,
    ushort2* __restrict__ xb, int total2) {
  int i = blockIdx.x * 256 + threadIdx.x;
  if (i >= total2) return;
  float2 v = x[i];
  xb[i] = make_ushort2(f2b(v.x), f2b(v.y));
}

// deg[conv][src] += w over all convs
__global__ __launch_bounds__(256) void deg_all(const int* __restrict__ ei,
    const float* __restrict__ ew, float* __restrict__ deg, int E, int N, int total) {
  int g = blockIdx.x * 256 + threadIdx.x;
  if (g >= total) return;
  int conv = g / E;
  int e = g - conv * E;
  const int* srcv = ei + (size_t)conv * 2 * E;
  unsafeAtomicAdd(&deg[(size_t)conv * N + srcv[e]], ew[(size_t)conv * E + e]);
}

__global__ __launch_bounds__(256) void diag_finish(float* __restrict__ diag, int total) {
  int p = blockIdx.x * 256 + threadIdx.x;
  if (p >= total) return;
  diag[p] = diag[p] - 1.0f;
}

// w0s = Σ_i W[i,0]; bs = Σ_i b[i]
__global__ __launch_bounds__(256) void wsum_kernel(const float* __restrict__ W,
    const float* __restrict__ b, float* __restrict__ w0s, float* __restrict__ bs,
    int KK, int NCv) {
  int p = blockIdx.x * 256 + threadIdx.x;
  if (p < CDIM * CDIM) {
    float s = 0.f;
    for (int i = 0; i < NCv; ++i) s += W[(size_t)i * KK * CDIM * CDIM + p];
    w0s[p] = s;
  }
  if (p < CDIM) {
    float s = 0.f;
    for (int i = 0; i < NCv; ++i) s += b[i * CDIM + p];
    bs[p] = s;
  }
}

// histogram of dst per conv
__global__ __launch_bounds__(256) void hist_all(const int* __restrict__ ei,
    int* __restrict__ cnt, int E, int N, int total) {
  int g = blockIdx.x * 256 + threadIdx.x;
  if (g >= total) return;
  int conv = g / E;
  int e = g - conv * E;
  const int* dstv = ei + (size_t)conv * 2 * E + E;
  atomicAdd(&cnt[(size_t)conv * N + dstv[e]], 1);
}

// per-conv exclusive scan (blockIdx = conv), wave-shuffle based
__global__ __launch_bounds__(1024) void scan_all(const int* __restrict__ cnt,
    int* __restrict__ row_ptr, int* __restrict__ pos, int N) {
  int conv = blockIdx.x;
  const int* c = cnt + (size_t)conv * N;
  int* rp = row_ptr + (size_t)conv * (N + 1);
  int* ps = pos + (size_t)conv * N;
  __shared__ int wsum[16];
  __shared__ int carry_s;
  if (threadIdx.x == 0) carry_s = 0;
  int lane = threadIdx.x & 63, wid = threadIdx.x >> 6;
  __syncthreads();
  for (int base = 0; base < N; base += 1024) {
    int i = base + (int)threadIdx.x;
    int v = (i < N) ? c[i] : 0;
    int s = v;
    #pragma unroll
    for (int off = 1; off < 64; off <<= 1) {
      int t = __shfl_up(s, off, 64);
      if (lane >= off) s += t;
    }
    if (lane == 63) wsum[wid] = s;
    __syncthreads();
    if (wid == 0) {
      int ws = (lane < 16) ? wsum[lane] : 0;
      #pragma unroll
      for (int off = 1; off < 16; off <<= 1) {
        int t = __shfl_up(ws, off, 64);
        if (lane >= off) ws += t;
      }
      if (lane < 16) wsum[lane] = ws;  // inclusive over waves
    }
    __syncthreads();
    int woff = (wid == 0) ? 0 : wsum[wid - 1];
    int excl = carry_s + woff + s - v;
    if (i < N) { rp[i] = excl; ps[i] = excl; }
    __syncthreads();
    if (threadIdx.x == 0) carry_s += wsum[15];
    __syncthreads();
  }
  if (threadIdx.x == 0) rp[N] = carry_s;
}

// place (src, w) into dst-sorted CSR
__global__ __launch_bounds__(256) void fill_all(const int* __restrict__ ei,
    const float* __restrict__ ew, int* __restrict__ pos, int2* __restrict__ srcw,
    int E, int N, int total) {
  int g = blockIdx.x * 256 + threadIdx.x;
  if (g >= total) return;
  int conv = g / E;
  int e = g - conv * E;
  const int* srcv = ei + (size_t)conv * 2 * E;
  const int* dstv = srcv + E;
  int p = atomicAdd(&pos[(size_t)conv * N + dstv[e]], 1);
  srcw[(size_t)conv * E + p] = make_int2(srcv[e], __float_as_int(ew[(size_t)conv * E + e]));
}

// Tx1_i = lhat_i(x) for all convs. One wave (64 lanes, ushort2 cols) per row.
__global__ __launch_bounds__(256) void spmvA(const int* __restrict__ row_ptr,
    const int2* __restrict__ srcw, const float* __restrict__ diag,
    const ushort2* __restrict__ xb, ushort2* __restrict__ tx1b, int N, int E, int NCv) {
  int rg = blockIdx.x * 4 + ((int)threadIdx.x >> 6);
  if (rg >= NCv * N) return;
  int conv = rg / N;
  int row = rg - conv * N;
  const int* rp = row_ptr + (size_t)conv * (N + 1);
  const int2* sw = srcw + (size_t)conv * E;
  ushort2* O = tx1b + (size_t)conv * N * 64;
  int c2 = threadIdx.x & 63;
  float d = diag[(size_t)conv * N + row];
  ushort2 xv = xb[(size_t)row * 64 + c2];
  float ax = d * b2f(xv.x), ay = d * b2f(xv.y);
  int e = rp[row], end = rp[row + 1];
  for (; e + 1 < end; e += 2) {
    int2 s0 = sw[e], s1 = sw[e + 1];
    ushort2 v0 = xb[(size_t)s0.x * 64 + c2];
    ushort2 v1 = xb[(size_t)s1.x * 64 + c2];
    float w0 = __int_as_float(s0.y), w1 = __int_as_float(s1.y);
    ax = fmaf(-w0, b2f(v0.x), ax); ay = fmaf(-w0, b2f(v0.y), ay);
    ax = fmaf(-w1, b2f(v1.x), ax); ay = fmaf(-w1, b2f(v1.y), ay);
  }
  if (e < end) {
    int2 s0 = sw[e];
    ushort2 v0 = xb[(size_t)s0.x * 64 + c2];
    float w0 = __int_as_float(s0.y);
    ax = fmaf(-w0, b2f(v0.x), ax); ay = fmaf(-w0, b2f(v0.y), ay);
  }
  O[(size_t)row * 64 + c2] = make_ushort2(f2b(ax), f2b(ay));
}

// Tx2 = 2*lhat(Tx1_i) - x  (single conv)
__global__ __launch_bounds__(256) void spmvB(const int* __restrict__ rp,
    const int2* __restrict__ sw, const float* __restrict__ diag,
    const ushort2* __restrict__ t1, const ushort2* __restrict__ xb,
    ushort2* __restrict__ t2, int N) {
  int row = blockIdx.x * 4 + ((int)threadIdx.x >> 6);
  if (row >= N) return;
  int c2 = threadIdx.x & 63;
  float d = diag[row];
  ushort2 tv = t1[(size_t)row * 64 + c2];
  float ax = d * b2f(tv.x), ay = d * b2f(tv.y);
  int e = rp[row], end = rp[row + 1];
  for (; e + 1 < end; e += 2) {
    int2 s0 = sw[e], s1 = sw[e + 1];
    ushort2 v0 = t1[(size_t)s0.x * 64 + c2];
    ushort2 v1 = t1[(size_t)s1.x * 64 + c2];
    float w0 = __int_as_float(s0.y), w1 = __int_as_float(s1.y);
    ax = fmaf(-w0, b2f(v0.x), ax); ay = fmaf(-w0, b2f(v0.y), ay);
    ax = fmaf(-w1, b2f(v1.x), ax); ay = fmaf(-w1, b2f(v1.y), ay);
  }
  if (e < end) {
    int2 s0 = sw[e];
    ushort2 v0 = t1[(size_t)s0.x * 64 + c2];
    float w0 = __int_as_float(s0.y);
    ax = fmaf(-w0, b2f(v0.x), ax); ay = fmaf(-w0, b2f(v0.y), ay);
  }
  ushort2 xv = xb[(size_t)row * 64 + c2];
  ax = 2.f * ax - b2f(xv.x);
  ay = 2.f * ay - b2f(xv.y);
  t2[(size_t)row * 64 + c2] = make_ushort2(f2b(ax), f2b(ay));
}

// C = A(bf16) @ B(f32) + bias  (write)
__global__ __launch_bounds__(256) void gemm_init(const ushort2* __restrict__ A,
    const float* __restrict__ B, const float* __restrict__ bias,
    float* __restrict__ C, int N) {
  __shared__ float Al[32 * CDIM];
  int t = threadIdx.x;
  int row0 = blockIdx.x * 32;
  #pragma unroll
  for (int j = 0; j < 8; ++j) {
    int idx2 = t + j * 256;
    int rl = idx2 >> 6, c2 = idx2 & 63;
    int r = row0 + rl;
    ushort2 v = (r < N) ? A[(size_t)r * 64 + c2] : make_ushort2(0, 0);
    Al[rl * CDIM + c2 * 2] = b2f(v.x);
    Al[rl * CDIM + c2 * 2 + 1] = b2f(v.y);
  }
  __syncthreads();
  int c = t & 127;
  int rb = (t >> 7) * 16;
  float acc[16];
  #pragma unroll
  for (int j = 0; j < 16; ++j) acc[j] = 0.f;
  for (int k = 0; k < CDIM; k += 4) {
    float b0 = B[(k + 0) * CDIM + c];
    float b1 = B[(k + 1) * CDIM + c];
    float b2 = B[(k + 2) * CDIM + c];
    float b3 = B[(k + 3) * CDIM + c];
    #pragma unroll
    for (int j = 0; j < 16; ++j) {
      const float4 a = *reinterpret_cast<const float4*>(&Al[(rb + j) * CDIM + k]);
      acc[j] = fmaf(a.x, b0, fmaf(a.y, b1, fmaf(a.z, b2, fmaf(a.w, b3, acc[j]))));
    }
  }
  float bb = bias[c];
  #pragma unroll
  for (int j = 0; j < 16; ++j) {
    int r = row0 + rb + j;
    if (r < N) C[(size_t)r * CDIM + c] = acc[j] + bb;
  }
}

// C += A1(bf16)@B1(f32) + A2(bf16)@B2(f32)
__global__ __launch_bounds__(256) void gemm2(const ushort2* __restrict__ A1,
    const ushort2* __restrict__ A2, const float* __restrict__ B1,
    const float* __restrict__ B2, float* __restrict__ C, int N) {
  __shared__ float Al[2 * 32 * CDIM];
  int t = threadIdx.x;
  int row0 = blockIdx.x * 32;
  #pragma unroll
  for (int j = 0; j < 8; ++j) {
    int idx2 = t + j * 256;
    int rl = idx2 >> 6, c2 = idx2 & 63;
    int r = row0 + rl;
    ushort2 v1 = (r < N) ? A1[(size_t)r * 64 + c2] : make_ushort2(0, 0);
    ushort2 v2 = (r < N) ? A2[(size_t)r * 64 + c2] : make_ushort2(0, 0);
    Al[rl * CDIM + c2 * 2]     = b2f(v1.x);
    Al[rl * CDIM + c2 * 2 + 1] = b2f(v1.y);
    Al[4096 + rl * CDIM + c2 * 2]     = b2f(v2.x);
    Al[4096 + rl * CDIM + c2 * 2 + 1] = b2f(v2.y);
  }
  __syncthreads();
  int c = t & 127;
  int rb = (t >> 7) * 16;
  float acc[16];
  #pragma unroll
  for (int j = 0; j < 16; ++j) acc[j] = 0.f;
  for (int k = 0; k < CDIM; k += 4) {
    float b10 = B1[(k + 0) * CDIM + c];
    float b11 = B1[(k + 1) * CDIM + c];
    float b12 = B1[(k + 2) * CDIM + c];
    float b13 = B1[(k + 3) * CDIM + c];
    float b20 = B2[(k + 0) * CDIM + c];
    float b21 = B2[(k + 1) * CDIM + c];
    float b22 = B2[(k + 2) * CDIM + c];
    float b23 = B2[(k + 3) * CDIM + c];
    #pragma unroll
    for (int j = 0; j < 16; ++j) {
      const float4 a1 = *reinterpret_cast<const float4*>(&Al[(rb + j) * CDIM + k]);
      const float4 a2 = *reinterpret_cast<const float4*>(&Al[4096 + (rb + j) * CDIM + k]);
      float s = acc[j];
      s = fmaf(a1.x, b10, s); s = fmaf(a1.y, b11, s);
      s = fmaf(a1.z, b12, s); s = fmaf(a1.w, b13, s);
      s = fmaf(a2.x, b20, s); s = fmaf(a2.y, b21, s);
      s = fmaf(a2.z, b22, s); s = fmaf(a2.w, b23, s);
      acc[j] = s;
    }
  }
  #pragma unroll
  for (int j = 0; j < 16; ++j) {
    int r = row0 + rb + j;
    if (r < N) C[(size_t)r * CDIM + c] += acc[j];
  }
}

extern "C" void kernel_launch(void* const* d_in, const int* in_sizes, int n_in,
                              void* d_out, int out_size, void* d_ws, size_t ws_size,
                              hipStream_t stream) {
  const float* x  = (const float*)d_in[0];
  const int*   ei = (const int*)d_in[1];    // [NC, 2, E] int32
  const float* ew = (const float*)d_in[2];  // [NC, E]
  const float* W  = (const float*)d_in[3];  // [NC, K, 128, 128]
  const float* b  = (const float*)d_in[4];  // [NC, 128]

  const int Nn  = in_sizes[0] / CDIM;
  const int NCv = in_sizes[4] / CDIM;
  const int E   = in_sizes[2] / NCv;
  const int KK  = in_sizes[3] / (NCv * CDIM * CDIM);

  char* p = (char*)d_ws;
  auto take = [&](size_t bytes) { char* q = p; p += (bytes + 255) & ~(size_t)255; return q; };
  float* diag    = (float*)take((size_t)NCv * Nn * 4);
  int*   cntpos  = (int*)take((size_t)NCv * Nn * 4);
  int*   row_ptr = (int*)take((size_t)NCv * (Nn + 1) * 4);
  float* w0s     = (float*)take(CDIM * CDIM * 4);
  float* bs      = (float*)take(CDIM * 4);
  ushort2* xb    = (ushort2*)take((size_t)Nn * 64 * 4);
  ushort2* tx1b  = (ushort2*)take((size_t)NCv * Nn * 64 * 4);
  ushort2* tx2b  = (ushort2*)take((size_t)Nn * 64 * 4);
  int2*  srcw    = (int2*)take((size_t)NCv * E * 8);

  const int totE = NCv * E;
  const int eg = (totE + 255) / 256;

  hipMemsetAsync(diag, 0, (size_t)NCv * Nn * 4, stream);
  hipMemsetAsync(cntpos, 0, (size_t)NCv * Nn * 4, stream);

  xcast_kernel<<<(Nn * 64 + 255) / 256, 256, 0, stream>>>(
      (const float2*)x, xb, Nn * 64);
  deg_all<<<eg, 256, 0, stream>>>(ei, ew, diag, E, Nn, totE);
  diag_finish<<<(NCv * Nn + 255) / 256, 256, 0, stream>>>(diag, NCv * Nn);
  wsum_kernel<<<(CDIM * CDIM + 255) / 256, 256, 0, stream>>>(W, b, w0s, bs, KK, NCv);
  hist_all<<<eg, 256, 0, stream>>>(ei, cntpos, E, Nn, totE);
  scan_all<<<NCv, 1024, 0, stream>>>(cntpos, row_ptr, cntpos, Nn);
  fill_all<<<eg, 256, 0, stream>>>(ei, ew, cntpos, srcw, E, Nn, totE);

  // Tx1 for all convs in one launch
  spmvA<<<(NCv * Nn + 3) / 4, 256, 0, stream>>>(row_ptr, srcw, diag, xb, tx1b,
                                                Nn, E, NCv);

  const int gemm_grid = (Nn + 31) / 32;
  gemm_init<<<gemm_grid, 256, 0, stream>>>(xb, w0s, bs, (float*)d_out, Nn);

  for (int i = 0; i < NCv; ++i) {
    const int* rp = row_ptr + (size_t)i * (Nn + 1);
    const int2* sw = srcw + (size_t)i * E;
    const float* di = diag + (size_t)i * Nn;
    const ushort2* t1 = tx1b + (size_t)i * Nn * 64;
    const float* Wi = W + (size_t)i * KK * CDIM * CDIM;

    spmvB<<<(Nn + 3) / 4, 256, 0, stream>>>(rp, sw, di, t1, xb, tx2b, Nn);
    gemm2<<<gemm_grid, 256, 0, stream>>>(t1, tx2b, Wi + (size_t)1 * CDIM * CDIM,
                                         Wi + (size_t)2 * CDIM * CDIM,
                                         (float*)d_out, Nn);
  }
}

// Round 4
// 921.439 us; speedup vs baseline: 9.2580x; 1.1859x over previous
//
#include <hip/hip_runtime.h>

// out = Σ_i ChebConv_i(x), K=3, normalization=None, lambda_max=2 (scale=1).
// lhat(v)[r] = (deg[r]-1)*v[r] - Σ_{e:dst=r} w_e v[src_e]
// Tx1 = lhat(x); Tx2 = 2*lhat(Tx1) - x
// out = x@ΣW[i,0] + Σ_i (Tx1_i@W[i,1] + Tx2_i@W[i,2]) + Σ_i b_i
//
// Round 4: XCD-sliced CSR fill (kill 8x write amplification), fused deg+hist,
// 2-rows-per-wave spmv (2x memory-level parallelism).

#define CDIM 128

__device__ __forceinline__ float b2f(unsigned short h) {
  return __uint_as_float((unsigned)h << 16);
}
__device__ __forceinline__ unsigned short f2b(float f) {
  unsigned u = __float_as_uint(f);
  return (unsigned short)((u + 0x7FFF + ((u >> 16) & 1)) >> 16);
}

// x (f32) -> xb (bf16 pairs)
__global__ __launch_bounds__(256) void xcast_kernel(const float2* __restrict__ x,
    ushort2* __restrict__ xb, int total2) {
  int i = blockIdx.x * 256 + threadIdx.x;
  if (i >= total2) return;
  float2 v = x[i];
  xb[i] = make_ushort2(f2b(v.x), f2b(v.y));
}

// fused: deg[conv][src] += w ; cnt[conv][dst] += 1  (one pass over edges)
__global__ __launch_bounds__(256) void prep_all(const int* __restrict__ ei,
    const float* __restrict__ ew, float* __restrict__ deg, int* __restrict__ cnt,
    int E, int N, int NCv) {
  int g = blockIdx.x * 256 + threadIdx.x;
  int stride = gridDim.x * 256;
  for (int conv = 0; conv < NCv; ++conv) {
    const int* srcv = ei + (size_t)conv * 2 * E;
    const int* dstv = srcv + E;
    const float* w = ew + (size_t)conv * E;
    float* dg = deg + (size_t)conv * N;
    int* cc = cnt + (size_t)conv * N;
    for (int e = g; e < E; e += stride) {
      unsafeAtomicAdd(&dg[srcv[e]], w[e]);
      atomicAdd(&cc[dstv[e]], 1);
    }
  }
}

// per-conv exclusive scan (blockIdx = conv) + diag finish (diag = deg-1)
__global__ __launch_bounds__(1024) void scan_all(const int* __restrict__ cnt,
    int* __restrict__ row_ptr, int* __restrict__ pos, float* __restrict__ diag, int N) {
  int conv = blockIdx.x;
  const int* c = cnt + (size_t)conv * N;
  int* rp = row_ptr + (size_t)conv * (N + 1);
  int* ps = pos + (size_t)conv * N;
  float* dg = diag + (size_t)conv * N;
  for (int i = threadIdx.x; i < N; i += 1024) dg[i] -= 1.0f;
  __shared__ int wsum[16];
  __shared__ int carry_s;
  if (threadIdx.x == 0) carry_s = 0;
  int lane = threadIdx.x & 63, wid = threadIdx.x >> 6;
  __syncthreads();
  for (int base = 0; base < N; base += 1024) {
    int i = base + (int)threadIdx.x;
    int v = (i < N) ? c[i] : 0;
    int s = v;
    #pragma unroll
    for (int off = 1; off < 64; off <<= 1) {
      int t = __shfl_up(s, off, 64);
      if (lane >= off) s += t;
    }
    if (lane == 63) wsum[wid] = s;
    __syncthreads();
    if (wid == 0) {
      int ws = (lane < 16) ? wsum[lane] : 0;
      #pragma unroll
      for (int off = 1; off < 16; off <<= 1) {
        int t = __shfl_up(ws, off, 64);
        if (lane >= off) ws += t;
      }
      if (lane < 16) wsum[lane] = ws;
    }
    __syncthreads();
    int woff = (wid == 0) ? 0 : wsum[wid - 1];
    int excl = carry_s + woff + s - v;
    if (i < N) { rp[i] = excl; ps[i] = excl; }
    __syncthreads();
    if (threadIdx.x == 0) carry_s += wsum[15];
    __syncthreads();
  }
  if (threadIdx.x == 0) rp[N] = carry_s;
}

// w0s = Σ_i W[i,0]; bs = Σ_i b[i]
__global__ __launch_bounds__(256) void wsum_kernel(const float* __restrict__ W,
    const float* __restrict__ b, float* __restrict__ w0s, float* __restrict__ bs,
    int KK, int NCv) {
  int p = blockIdx.x * 256 + threadIdx.x;
  if (p < CDIM * CDIM) {
    float s = 0.f;
    for (int i = 0; i < NCv; ++i) s += W[(size_t)i * KK * CDIM * CDIM + p];
    w0s[p] = s;
  }
  if (p < CDIM) {
    float s = 0.f;
    for (int i = 0; i < NCv; ++i) s += b[i * CDIM + p];
    bs[p] = s;
  }
}

// XCD-sliced CSR fill: block b only places edges whose dst is in slice b&7.
// With round-robin blockIdx->XCD dispatch, each XCD's scattered srcw writes
// stay in its own L2 slice (~2.4MB < 4MiB) -> full-line writebacks.
__global__ __launch_bounds__(256) void fill_sliced(const int* __restrict__ ei,
    const float* __restrict__ ew, int* __restrict__ pos, int2* __restrict__ srcw,
    int E, int N, int NCv, float inv8) {
  const int slice = blockIdx.x & 7;
  const int g0 = (blockIdx.x >> 3) * 256 + threadIdx.x;
  const int stride = (gridDim.x >> 3) * 256;
  for (int conv = 0; conv < NCv; ++conv) {
    const int* srcv = ei + (size_t)conv * 2 * E;
    const int* dstv = srcv + E;
    const float* w = ew + (size_t)conv * E;
    int* ps = pos + (size_t)conv * N;
    int2* sw = srcw + (size_t)conv * E;
    for (int e = g0; e < E; e += stride) {
      int d = dstv[e];
      int s = (int)(d * inv8);
      s = s > 7 ? 7 : s;
      if (s != slice) continue;
      int p = atomicAdd(&ps[d], 1);
      sw[p] = make_int2(srcv[e], __float_as_int(w[e]));
    }
  }
}

// Tx1_i = lhat_i(x) for all convs. 2 rows per wave: 32 lanes x ushort4 per row.
__global__ __launch_bounds__(256) void spmvA(const int* __restrict__ row_ptr,
    const int2* __restrict__ srcw, const float* __restrict__ diag,
    const ushort4* __restrict__ xb, ushort4* __restrict__ tx1b, int N, int E, int NCv) {
  int rg = blockIdx.x * 8 + ((int)threadIdx.x >> 5);
  if (rg >= NCv * N) return;
  int conv = rg / N;
  int row = rg - conv * N;
  const int* rp = row_ptr + (size_t)conv * (N + 1);
  const int2* sw = srcw + (size_t)conv * E;
  int c4 = threadIdx.x & 31;
  float d = diag[(size_t)conv * N + row];
  ushort4 xv = xb[(size_t)row * 32 + c4];
  float a0 = d * b2f(xv.x), a1 = d * b2f(xv.y);
  float a2 = d * b2f(xv.z), a3 = d * b2f(xv.w);
  int e = rp[row], end = rp[row + 1];
  for (; e + 1 < end; e += 2) {
    int2 s0 = sw[e], s1 = sw[e + 1];
    ushort4 v0 = xb[(size_t)s0.x * 32 + c4];
    ushort4 v1 = xb[(size_t)s1.x * 32 + c4];
    float w0 = __int_as_float(s0.y), w1 = __int_as_float(s1.y);
    a0 = fmaf(-w0, b2f(v0.x), a0); a1 = fmaf(-w0, b2f(v0.y), a1);
    a2 = fmaf(-w0, b2f(v0.z), a2); a3 = fmaf(-w0, b2f(v0.w), a3);
    a0 = fmaf(-w1, b2f(v1.x), a0); a1 = fmaf(-w1, b2f(v1.y), a1);
    a2 = fmaf(-w1, b2f(v1.z), a2); a3 = fmaf(-w1, b2f(v1.w), a3);
  }
  if (e < end) {
    int2 s0 = sw[e];
    ushort4 v0 = xb[(size_t)s0.x * 32 + c4];
    float w0 = __int_as_float(s0.y);
    a0 = fmaf(-w0, b2f(v0.x), a0); a1 = fmaf(-w0, b2f(v0.y), a1);
    a2 = fmaf(-w0, b2f(v0.z), a2); a3 = fmaf(-w0, b2f(v0.w), a3);
  }
  tx1b[((size_t)conv * N + row) * 32 + c4] =
      make_ushort4(f2b(a0), f2b(a1), f2b(a2), f2b(a3));
}

// Tx2 = 2*lhat(Tx1_i) - x  (single conv), same 2-rows-per-wave layout
__global__ __launch_bounds__(256) void spmvB(const int* __restrict__ rp,
    const int2* __restrict__ sw, const float* __restrict__ diag,
    const ushort4* __restrict__ t1, const ushort4* __restrict__ xb,
    ushort4* __restrict__ t2, int N) {
  int row = blockIdx.x * 8 + ((int)threadIdx.x >> 5);
  if (row >= N) return;
  int c4 = threadIdx.x & 31;
  float d = diag[row];
  ushort4 tv = t1[(size_t)row * 32 + c4];
  float a0 = d * b2f(tv.x), a1 = d * b2f(tv.y);
  float a2 = d * b2f(tv.z), a3 = d * b2f(tv.w);
  int e = rp[row], end = rp[row + 1];
  for (; e + 1 < end; e += 2) {
    int2 s0 = sw[e], s1 = sw[e + 1];
    ushort4 v0 = t1[(size_t)s0.x * 32 + c4];
    ushort4 v1 = t1[(size_t)s1.x * 32 + c4];
    float w0 = __int_as_float(s0.y), w1 = __int_as_float(s1.y);
    a0 = fmaf(-w0, b2f(v0.x), a0); a1 = fmaf(-w0, b2f(v0.y), a1);
    a2 = fmaf(-w0, b2f(v0.z), a2); a3 = fmaf(-w0, b2f(v0.w), a3);
    a0 = fmaf(-w1, b2f(v1.x), a0); a1 = fmaf(-w1, b2f(v1.y), a1);
    a2 = fmaf(-w1, b2f(v1.z), a2); a3 = fmaf(-w1, b2f(v1.w), a3);
  }
  if (e < end) {
    int2 s0 = sw[e];
    ushort4 v0 = t1[(size_t)s0.x * 32 + c4];
    float w0 = __int_as_float(s0.y);
    a0 = fmaf(-w0, b2f(v0.x), a0); a1 = fmaf(-w0, b2f(v0.y), a1);
    a2 = fmaf(-w0, b2f(v0.z), a2); a3 = fmaf(-w0, b2f(v0.w), a3);
  }
  ushort4 xv = xb[(size_t)row * 32 + c4];
  a0 = 2.f * a0 - b2f(xv.x); a1 = 2.f * a1 - b2f(xv.y);
  a2 = 2.f * a2 - b2f(xv.z); a3 = 2.f * a3 - b2f(xv.w);
  t2[(size_t)row * 32 + c4] = make_ushort4(f2b(a0), f2b(a1), f2b(a2), f2b(a3));
}

// C = A(bf16) @ B(f32) + bias  (write)
__global__ __launch_bounds__(256) void gemm_init(const ushort2* __restrict__ A,
    const float* __restrict__ B, const float* __restrict__ bias,
    float* __restrict__ C, int N) {
  __shared__ float Al[32 * CDIM];
  int t = threadIdx.x;
  int row0 = blockIdx.x * 32;
  #pragma unroll
  for (int j = 0; j < 8; ++j) {
    int idx2 = t + j * 256;
    int rl = idx2 >> 6, c2 = idx2 & 63;
    int r = row0 + rl;
    ushort2 v = (r < N) ? A[(size_t)r * 64 + c2] : make_ushort2(0, 0);
    Al[rl * CDIM + c2 * 2] = b2f(v.x);
    Al[rl * CDIM + c2 * 2 + 1] = b2f(v.y);
  }
  __syncthreads();
  int c = t & 127;
  int rb = (t >> 7) * 16;
  float acc[16];
  #pragma unroll
  for (int j = 0; j < 16; ++j) acc[j] = 0.f;
  for (int k = 0; k < CDIM; k += 4) {
    float b0 = B[(k + 0) * CDIM + c];
    float b1 = B[(k + 1) * CDIM + c];
    float b2 = B[(k + 2) * CDIM + c];
    float b3 = B[(k + 3) * CDIM + c];
    #pragma unroll
    for (int j = 0; j < 16; ++j) {
      const float4 a = *reinterpret_cast<const float4*>(&Al[(rb + j) * CDIM + k]);
      acc[j] = fmaf(a.x, b0, fmaf(a.y, b1, fmaf(a.z, b2, fmaf(a.w, b3, acc[j]))));
    }
  }
  float bb = bias[c];
  #pragma unroll
  for (int j = 0; j < 16; ++j) {
    int r = row0 + rb + j;
    if (r < N) C[(size_t)r * CDIM + c] = acc[j] + bb;
  }
}

// C += A1(bf16)@B1(f32) + A2(bf16)@B2(f32)
__global__ __launch_bounds__(256) void gemm2(const ushort2* __restrict__ A1,
    const ushort2* __restrict__ A2, const float* __restrict__ B1,
    const float* __restrict__ B2, float* __restrict__ C, int N) {
  __shared__ float Al[2 * 32 * CDIM];
  int t = threadIdx.x;
  int row0 = blockIdx.x * 32;
  #pragma unroll
  for (int j = 0; j < 8; ++j) {
    int idx2 = t + j * 256;
    int rl = idx2 >> 6, c2 = idx2 & 63;
    int r = row0 + rl;
    ushort2 v1 = (r < N) ? A1[(size_t)r * 64 + c2] : make_ushort2(0, 0);
    ushort2 v2 = (r < N) ? A2[(size_t)r * 64 + c2] : make_ushort2(0, 0);
    Al[rl * CDIM + c2 * 2]     = b2f(v1.x);
    Al[rl * CDIM + c2 * 2 + 1] = b2f(v1.y);
    Al[4096 + rl * CDIM + c2 * 2]     = b2f(v2.x);
    Al[4096 + rl * CDIM + c2 * 2 + 1] = b2f(v2.y);
  }
  __syncthreads();
  int c = t & 127;
  int rb = (t >> 7) * 16;
  float acc[16];
  #pragma unroll
  for (int j = 0; j < 16; ++j) acc[j] = 0.f;
  for (int k = 0; k < CDIM; k += 4) {
    float b10 = B1[(k + 0) * CDIM + c];
    float b11 = B1[(k + 1) * CDIM + c];
    float b12 = B1[(k + 2) * CDIM + c];
    float b13 = B1[(k + 3) * CDIM + c];
    float b20 = B2[(k + 0) * CDIM + c];
    float b21 = B2[(k + 1) * CDIM + c];
    float b22 = B2[(k + 2) * CDIM + c];
    float b23 = B2[(k + 3) * CDIM + c];
    #pragma unroll
    for (int j = 0; j < 16; ++j) {
      const float4 a1 = *reinterpret_cast<const float4*>(&Al[(rb + j) * CDIM + k]);
      const float4 a2 = *reinterpret_cast<const float4*>(&Al[4096 + (rb + j) * CDIM + k]);
      float s = acc[j];
      s = fmaf(a1.x, b10, s); s = fmaf(a1.y, b11, s);
      s = fmaf(a1.z, b12, s); s = fmaf(a1.w, b13, s);
      s = fmaf(a2.x, b20, s); s = fmaf(a2.y, b21, s);
      s = fmaf(a2.z, b22, s); s = fmaf(a2.w, b23, s);
      acc[j] = s;
    }
  }
  #pragma unroll
  for (int j = 0; j < 16; ++j) {
    int r = row0 + rb + j;
    if (r < N) C[(size_t)r * CDIM + c] += acc[j];
  }
}

extern "C" void kernel_launch(void* const* d_in, const int* in_sizes, int n_in,
                              void* d_out, int out_size, void* d_ws, size_t ws_size,
                              hipStream_t stream) {
  const float* x  = (const float*)d_in[0];
  const int*   ei = (const int*)d_in[1];    // [NC, 2, E] int32
  const float* ew = (const float*)d_in[2];  // [NC, E]
  const float* W  = (const float*)d_in[3];  // [NC, K, 128, 128]
  const float* b  = (const float*)d_in[4];  // [NC, 128]

  const int Nn  = in_sizes[0] / CDIM;
  const int NCv = in_sizes[4] / CDIM;
  const int E   = in_sizes[2] / NCv;
  const int KK  = in_sizes[3] / (NCv * CDIM * CDIM);

  char* p = (char*)d_ws;
  auto take = [&](size_t bytes) { char* q = p; p += (bytes + 255) & ~(size_t)255; return q; };
  float* diag    = (float*)take((size_t)NCv * Nn * 4);
  int*   cntpos  = (int*)take((size_t)NCv * Nn * 4);
  int*   row_ptr = (int*)take((size_t)NCv * (Nn + 1) * 4);
  float* w0s     = (float*)take(CDIM * CDIM * 4);
  float* bs      = (float*)take(CDIM * 4);
  ushort2* xb    = (ushort2*)take((size_t)Nn * 64 * 4);
  ushort2* tx1b  = (ushort2*)take((size_t)NCv * Nn * 64 * 4);
  ushort2* tx2b  = (ushort2*)take((size_t)Nn * 64 * 4);
  int2*  srcw    = (int2*)take((size_t)NCv * E * 8);

  hipMemsetAsync(diag, 0, (size_t)NCv * Nn * 4, stream);
  hipMemsetAsync(cntpos, 0, (size_t)NCv * Nn * 4, stream);

  xcast_kernel<<<(Nn * 64 + 255) / 256, 256, 0, stream>>>(
      (const float2*)x, xb, Nn * 64);
  prep_all<<<2048, 256, 0, stream>>>(ei, ew, diag, cntpos, E, Nn, NCv);
  scan_all<<<NCv, 1024, 0, stream>>>(cntpos, row_ptr, cntpos, diag, Nn);
  wsum_kernel<<<(CDIM * CDIM + 255) / 256, 256, 0, stream>>>(W, b, w0s, bs, KK, NCv);
  fill_sliced<<<2048, 256, 0, stream>>>(ei, ew, cntpos, srcw, E, Nn, NCv,
                                        8.0f / (float)Nn);

  // Tx1 for all convs in one launch (2 rows per wave)
  spmvA<<<(NCv * Nn + 7) / 8, 256, 0, stream>>>(row_ptr, srcw, diag,
      (const ushort4*)xb, (ushort4*)tx1b, Nn, E, NCv);

  const int gemm_grid = (Nn + 31) / 32;
  gemm_init<<<gemm_grid, 256, 0, stream>>>(xb, w0s, bs, (float*)d_out, Nn);

  for (int i = 0; i < NCv; ++i) {
    const int* rp = row_ptr + (size_t)i * (Nn + 1);
    const int2* sw = srcw + (size_t)i * E;
    const float* di = diag + (size_t)i * Nn;
    const ushort2* t1 = tx1b + (size_t)i * Nn * 64;
    const float* Wi = W + (size_t)i * KK * CDIM * CDIM;

    spmvB<<<(Nn + 7) / 8, 256, 0, stream>>>(rp, sw, di, (const ushort4*)t1,
        (const ushort4*)xb, (ushort4*)tx2b, Nn);
    gemm2<<<gemm_grid, 256, 0, stream>>>(t1, tx2b, Wi + (size_t)1 * CDIM * CDIM,
                                         Wi + (size_t)2 * CDIM * CDIM,
                                         (float*)d_out, Nn);
  }
}